// Round 6
// baseline (208.205 us; speedup 1.0000x reference)
//
#include <hip/hip_runtime.h>

#define BB 8
#define NN 8192
#define SS 2048
#define CC 256
#define KNN 8
#define TOPM 10       // per-chunk candidate count (top-8 + margin)
#define NCHUNK 4      // S split into 4 chunks of 512, one per wave
#define CH (SS / NCHUNK)
#define QPB 64        // queries per block (1 per lane)
#define MSTRIDE 41    // mbuf per-query stride (u32s): 41 mod 32 = 9 -> conflict-free
#define QTILE 32      // queries per accum tile
#define TILES_PER_B (NN / QTILE)   // 256

#define UMIN(a, b) __builtin_elementwise_min(a, b)
#define UMAX(a, b) __builtin_elementwise_max(a, b)
#define UMIN3(a, b, c) UMIN(UMIN(a, b), c)

typedef float v2f __attribute__((ext_vector_type(2)));

// ---------------- Kernel A: chunked branchless top-10 KNN + f64 re-rank -----
// 1 query/lane, wave w owns S-chunk w. SoA LDS + packed-f32 (v_pk) distances.
__global__ __launch_bounds__(256, 4) void knn_kernel(
    const float* __restrict__ xyz,   // [B,3,N]
    const float* __restrict__ sxyz,  // [B,3,S]
    int*   __restrict__ out_idx,     // [B,N,8]
    float* __restrict__ out_w)       // [B,N,8]
{
    __shared__ __align__(16) float sx[SS];      // 8 KB
    __shared__ __align__(16) float sy[SS];      // 8 KB
    __shared__ __align__(16) float szz[SS];     // 8 KB
    __shared__ unsigned mbuf[QPB * MSTRIDE];    // 10.5 KB

    const int b   = blockIdx.x >> 7;            // 128 blocks per batch
    const int q0  = (blockIdx.x & 127) * QPB;
    const int tid = threadIdx.x;
    const int wave = tid >> 6;
    const int lane = tid & 63;

    const float* sb = sxyz + (long)b * 3 * SS;
#pragma unroll
    for (int i = 0; i < SS / 256; ++i) {
        int s = tid + i * 256;
        sx[s]  = sb[s];
        sy[s]  = sb[SS + s];
        szz[s] = sb[2 * SS + s];
    }
    __syncthreads();

    const float* xb = xyz + (long)b * 3 * NN;
    const int n = q0 + lane;
    const float qx = xb[n], qy = xb[NN + n], qz = xb[2 * NN + n];
    const v2f qxv = {qx, qx}, qyv = {qy, qy}, qzv = {qz, qz};

    unsigned k1[TOPM];
#pragma unroll
    for (int j = 0; j < TOPM; ++j) k1[j] = 0xFFFFFFFFu;

    const int sbase = wave * CH;
#pragma unroll 2
    for (int i = 0; i < CH; i += 2) {
        const int s0 = sbase + i;
        const v2f px = *(const v2f*)&sx[s0];      // wave-uniform -> broadcast
        const v2f py = *(const v2f*)&sy[s0];
        const v2f pz = *(const v2f*)&szz[s0];
        v2f dx = px - qxv, dy = py - qyv, dz = pz - qzv;
        v2f d = dx * dx;
        d = __builtin_elementwise_fma(dy, dy, d);
        d = __builtin_elementwise_fma(dz, dz, d);
        unsigned c0 = (__float_as_uint(d.x) & 0xFFFFF800u) | (unsigned)s0;
        unsigned c1 = (__float_as_uint(d.y) & 0xFFFFF800u) | (unsigned)(s0 + 1);
        unsigned lo = UMIN(c0, c1), hi = UMAX(c0, c1);
#pragma unroll
        for (int j = TOPM - 1; j >= 2; --j)
            k1[j] = UMIN3(k1[j], UMAX(k1[j - 1], lo), UMAX(k1[j - 2], hi));
        k1[1] = UMIN3(k1[1], UMAX(k1[0], lo), hi);
        k1[0] = UMIN(k1[0], lo);
    }

    {
        unsigned* m1 = &mbuf[lane * MSTRIDE + wave * TOPM];
#pragma unroll
        for (int j = 0; j < TOPM; ++j) m1[j] = k1[j];
    }
    __syncthreads();

    // ---- Phase 2: one thread per query, f64 re-rank of 40 candidates ----
    if (tid < QPB) {
        const int nq = q0 + tid;
        const double dqx = (double)xb[nq], dqy = (double)xb[NN + nq], dqz = (double)xb[2 * NN + nq];
        const unsigned* ml = &mbuf[tid * MSTRIDE];

        unsigned long long top[KNN];
#pragma unroll
        for (int j = 0; j < KNN; ++j) top[j] = ~0ull;

        for (int j = 0; j < NCHUNK * TOPM; ++j) {
            unsigned key = ml[j];
            int s = key & 0x7FF;
            double ex = (double)sx[s] - dqx;
            double ey = (double)sy[s] - dqy;
            double ez = (double)szz[s] - dqz;
            double dd = ex * ex + ey * ey + ez * ez;
            unsigned long long c =
                (((unsigned long long)__double_as_longlong(dd)) & ~0x7FFull) | (unsigned long long)s;
#pragma unroll
            for (int jj = KNN - 1; jj >= 1; --jj)
                top[jj] = UMIN(UMAX(top[jj - 1], c), top[jj]);
            top[0] = UMIN(top[0], c);
        }

        // IDW weights (f32, identical to passing epilogue)
        const float fqx = xb[nq], fqy = xb[NN + nq], fqz = xb[2 * NN + nq];
        int   id[KNN];
        float inv[KNN];
        float ssum = 0.f;
#pragma unroll
        for (int k = 0; k < KNN; ++k) {
            id[k] = (int)(top[k] & 0x7FFull);
            float dx = sx[id[k]] - fqx, dy = sy[id[k]] - fqy, dz = szz[id[k]] - fqz;
            float dv = sqrtf(dx * dx + dy * dy + dz * dz);
            dv = fmaxf(dv, 1e-10f);
            inv[k] = 1.0f / dv;
            ssum += inv[k];
        }
        const float rs = 1.0f / ssum;
        const long base = ((long)b * NN + nq) * KNN;
#pragma unroll
        for (int k = 0; k < KNN; ++k) {
            out_idx[base + k] = id[k];
            out_w[base + k]   = inv[k] * rs;
        }
    }
}

// ---------------- Kernel B: sparse_feat [B,C,S] -> [B,S,C] + counter zero ---
__global__ __launch_bounds__(256) void transpose_kernel(
    const float* __restrict__ sf,   // [B,C,S]
    float* __restrict__ sfT,        // [B,S,C]
    int*   __restrict__ counters)   // [8] accum work-queue heads
{
    if (blockIdx.x == 0 && blockIdx.y == 0 && blockIdx.z == 0 &&
        threadIdx.y == 0 && threadIdx.x < 8)
        counters[threadIdx.x] = 0;

    __shared__ float tile[32][33];
    const int b  = blockIdx.z;
    const int c0 = blockIdx.y * 32;
    const int s0 = blockIdx.x * 32;
    const int tx = threadIdx.x, ty = threadIdx.y;   // (32, 8)
#pragma unroll
    for (int i = 0; i < 4; ++i) {
        int c = c0 + ty + i * 8;
        tile[ty + i * 8][tx] = sf[((long)b * CC + c) * SS + s0 + tx];
    }
    __syncthreads();
#pragma unroll
    for (int i = 0; i < 4; ++i) {
        int s = s0 + ty + i * 8;
        sfT[((long)b * SS + s) * CC + c0 + tx] = tile[tx][ty + i * 8];
    }
}

// ---------------- Kernel C: weighted gather-accumulate ----------------------
// XCD-affinity work queues: block pops a tile from its own XCD's batch queue
// (HW_REG_XCC_ID, id=20; wrong-id fallback = random affinity, still correct:
// atomic tickets are exactly-once and grid == total tiles). Output stores are
// non-temporal so the 2.1 MB/batch gather slice stays L2-resident.
__global__ __launch_bounds__(256) void accum_kernel(
    const float* __restrict__ sfT,  // [B,S,C]
    const int*   __restrict__ idx,  // [B,N,8]
    const float* __restrict__ wts,  // [B,N,8]
    float* __restrict__ out,        // [B,C,N]
    int*   __restrict__ counters)   // [8]
{
    __shared__ float4 tile4[QTILE * 65];   // 33.3 KB
    __shared__ int    sidx[QTILE * 8];
    __shared__ float  swts[QTILE * 8];
    __shared__ int    s_work;

    const int t = threadIdx.x;
    if (t == 0) {
        // simm16 = id | (offset<<6) | ((size-1)<<11); HW_REG_XCC_ID = 20
        unsigned xid = (unsigned)__builtin_amdgcn_s_getreg(20 | (0 << 6) | (31 << 11)) & 7u;
        int work = -1;
        for (int probe = 0; probe < 8; ++probe) {
            int q = (int)((xid + (unsigned)probe) & 7u);
            int ticket = atomicAdd(&counters[q], 1);
            if (ticket < TILES_PER_B) { work = q * TILES_PER_B + ticket; break; }
        }
        s_work = work;
    }
    __syncthreads();
    const int work = s_work;
    if (work < 0) return;                      // cannot happen (grid == tiles)
    const int b  = work >> 8;                  // TILES_PER_B = 256
    const int n0 = (work & (TILES_PER_B - 1)) * QTILE;

    const int wave = t >> 6;
    const int lane = t & 63;

    {
        long base = ((long)b * NN + n0) * KNN + t;   // 256 = 32*8 values
        sidx[t] = idx[base];
        swts[t] = wts[base];
    }
    __syncthreads();

    const float* fb = sfT + (long)b * SS * CC;

    float4 acc[8];
#pragma unroll
    for (int i = 0; i < 8; ++i) acc[i] = make_float4(0.f, 0.f, 0.f, 0.f);

#pragma unroll
    for (int i = 0; i < 8; ++i) {
        const int q = wave * 8 + i;
#pragma unroll
        for (int k = 0; k < KNN; ++k) {
            int   nid = sidx[q * KNN + k];           // broadcast
            float w   = swts[q * KNN + k];
            const float4 v = *(const float4*)(fb + (long)nid * CC + lane * 4);
            acc[i].x += w * v.x;
            acc[i].y += w * v.y;
            acc[i].z += w * v.z;
            acc[i].w += w * v.w;
        }
    }

#pragma unroll
    for (int i = 0; i < 8; ++i) {
        const int q = wave * 8 + i;
        tile4[q * 65 + lane] = acc[i];               // dense b128, conflict-free
    }
    __syncthreads();

    const float* tf = (const float*)tile4;
    const int j  = t & 31;                           // n offset (32 per tile)
    const int cb = t >> 5;                           // channel sub-index 0..7
#pragma unroll
    for (int r = 0; r < 32; ++r) {
        int c2 = r * 8 + cb;
        __builtin_nontemporal_store(tf[j * 260 + c2],
                                    &out[((long)b * CC + c2) * NN + n0 + j]);
    }
}

extern "C" void kernel_launch(void* const* d_in, const int* in_sizes, int n_in,
                              void* d_out, int out_size, void* d_ws, size_t ws_size,
                              hipStream_t stream) {
    const float* xyz  = (const float*)d_in[0];   // [8,3,8192]
    const float* sxyz = (const float*)d_in[1];   // [8,3,2048]
    const float* sf   = (const float*)d_in[2];   // [8,256,2048]
    float* out = (float*)d_out;                  // [8,256,8192]

    char* ws = (char*)d_ws;
    float* sfT  = (float*)ws;                                    // 16.78 MB
    int*   idxb = (int*)(ws + 16777216);                         // 2 MB
    float* wtsb = (float*)(ws + 16777216 + 2097152);             // 2 MB
    int*   cnts = (int*)(ws + 16777216 + 2097152 + 2097152);     // 32 B

    knn_kernel<<<dim3(BB * NN / QPB), dim3(256), 0, stream>>>(xyz, sxyz, idxb, wtsb);
    transpose_kernel<<<dim3(SS / 32, CC / 32, BB), dim3(32, 8), 0, stream>>>(sf, sfT, cnts);
    accum_kernel<<<dim3(BB * TILES_PER_B), dim3(256), 0, stream>>>(sfT, idxb, wtsb, out, cnts);
}

// Round 7
// 178.726 us; speedup vs baseline: 1.1649x; 1.1649x over previous
//
#include <hip/hip_runtime.h>
#include <hip/hip_fp16.h>

#define BB 8
#define NN 8192
#define SS 2048
#define CC 256
#define KNN 8
#define TOPM 10       // per-chunk candidate count (top-8 + margin)
#define NCHUNK 4      // S split into 4 chunks of 512, one per wave
#define CH (SS / NCHUNK)
#define QPB 64        // queries per block (1 per lane)
#define MSTRIDE 41    // mbuf per-query stride (u32s): 41 mod 32 = 9 -> conflict-free
#define FSTR 12       // feat LDS stride in halves (24 B): banks 6s mod 32 -> ~4-way

#define UMIN(a, b) __builtin_elementwise_min(a, b)
#define UMAX(a, b) __builtin_elementwise_max(a, b)
#define UMIN3(a, b, c) UMIN(UMIN(a, b), c)

__device__ __forceinline__ unsigned pack_h2(float a, float b) {
    __half2 h = __halves2half2(__float2half_rn(a), __float2half_rn(b));
    return *reinterpret_cast<unsigned*>(&h);
}
__device__ __forceinline__ float2 unpack_h2(unsigned u) {
    __half2 h = *reinterpret_cast<__half2*>(&u);
    return __half22float2(h);
}

// ---------------- Kernel A: chunked branchless top-10 KNN + f64 re-rank -----
// Exact round-5 structure (95.7 us); output packed as (f16 weight << 16) | idx.
__global__ __launch_bounds__(256, 4) void knn_kernel(
    const float* __restrict__ xyz,   // [B,3,N]
    const float* __restrict__ sxyz,  // [B,3,S]
    unsigned* __restrict__ out_pk)   // [B,N,8] packed
{
    __shared__ float2   sxy[SS];                // 16 KB
    __shared__ float    sz[SS];                 //  8 KB
    __shared__ unsigned mbuf[QPB * MSTRIDE];    // 10.5 KB

    const int b   = blockIdx.x >> 7;            // 128 blocks per batch
    const int q0  = (blockIdx.x & 127) * QPB;
    const int tid = threadIdx.x;
    const int wave = tid >> 6;
    const int lane = tid & 63;

    const float* sb = sxyz + (long)b * 3 * SS;
#pragma unroll
    for (int i = 0; i < SS / 256; ++i) {
        int s = tid + i * 256;
        sxy[s] = make_float2(sb[s], sb[SS + s]);
        sz[s]  = sb[2 * SS + s];
    }
    __syncthreads();

    const float* xb = xyz + (long)b * 3 * NN;
    const int n = q0 + lane;
    const float qx = xb[n], qy = xb[NN + n], qz = xb[2 * NN + n];

    unsigned k1[TOPM];
#pragma unroll
    for (int j = 0; j < TOPM; ++j) k1[j] = 0xFFFFFFFFu;

    const int sbase = wave * CH;
#pragma unroll 2
    for (int i = 0; i < CH; i += 2) {
        const int s0 = sbase + i;
        const float4 xy2 = *(const float4*)&sxy[s0];   // two points' x,y
        const float2 z2  = *(const float2*)&sz[s0];    // two points' z
        float dx0 = xy2.x - qx, dy0 = xy2.y - qy, dz0 = z2.x - qz;
        float dx1 = xy2.z - qx, dy1 = xy2.w - qy, dz1 = z2.y - qz;
        float d0 = fmaf(dx0, dx0, fmaf(dy0, dy0, dz0 * dz0));
        float d1 = fmaf(dx1, dx1, fmaf(dy1, dy1, dz1 * dz1));
        unsigned c0 = (__float_as_uint(d0) & 0xFFFFF800u) | (unsigned)s0;
        unsigned c1 = (__float_as_uint(d1) & 0xFFFFF800u) | (unsigned)(s0 + 1);
        unsigned lo = UMIN(c0, c1), hi = UMAX(c0, c1);
#pragma unroll
        for (int j = TOPM - 1; j >= 2; --j)
            k1[j] = UMIN3(k1[j], UMAX(k1[j - 1], lo), UMAX(k1[j - 2], hi));
        k1[1] = UMIN3(k1[1], UMAX(k1[0], lo), hi);
        k1[0] = UMIN(k1[0], lo);
    }

    {
        unsigned* m1 = &mbuf[lane * MSTRIDE + wave * TOPM];
#pragma unroll
        for (int j = 0; j < TOPM; ++j) m1[j] = k1[j];
    }
    __syncthreads();

    // ---- Phase 2: one thread per query, f64 re-rank of 40 candidates ----
    if (tid < QPB) {
        const int nq = q0 + tid;
        const double dqx = (double)xb[nq], dqy = (double)xb[NN + nq], dqz = (double)xb[2 * NN + nq];
        const unsigned* ml = &mbuf[tid * MSTRIDE];

        unsigned long long top[KNN];
#pragma unroll
        for (int j = 0; j < KNN; ++j) top[j] = ~0ull;

        for (int j = 0; j < NCHUNK * TOPM; ++j) {
            unsigned key = ml[j];
            int s = key & 0x7FF;
            float2 pxy = sxy[s];
            float  pz  = sz[s];
            double ex = (double)pxy.x - dqx;
            double ey = (double)pxy.y - dqy;
            double ez = (double)pz - dqz;
            double dd = ex * ex + ey * ey + ez * ez;
            unsigned long long c =
                (((unsigned long long)__double_as_longlong(dd)) & ~0x7FFull) | (unsigned long long)s;
#pragma unroll
            for (int jj = KNN - 1; jj >= 1; --jj)
                top[jj] = UMIN(UMAX(top[jj - 1], c), top[jj]);
            top[0] = UMIN(top[0], c);
        }

        // IDW weights (f32, identical math to passing epilogue)
        const float fqx = xb[nq], fqy = xb[NN + nq], fqz = xb[2 * NN + nq];
        int   id[KNN];
        float inv[KNN];
        float ssum = 0.f;
#pragma unroll
        for (int k = 0; k < KNN; ++k) {
            id[k] = (int)(top[k] & 0x7FFull);
            float2 pxy = sxy[id[k]];
            float  pz  = sz[id[k]];
            float dx = pxy.x - fqx, dy = pxy.y - fqy, dz = pz - fqz;
            float dv = sqrtf(dx * dx + dy * dy + dz * dz);
            dv = fmaxf(dv, 1e-10f);
            inv[k] = 1.0f / dv;
            ssum += inv[k];
        }
        const float rs = 1.0f / ssum;
        const long base = ((long)b * NN + nq) * KNN;
#pragma unroll
        for (int k = 0; k < KNN; ++k) {
            unsigned hw = (unsigned)__half_as_ushort(__float2half_rn(inv[k] * rs));
            out_pk[base + k] = (hw << 16) | (unsigned)id[k];
        }
    }
}

// ---------------- Kernel C: LDS-resident feature gather ---------------------
// Block = (batch, 8-channel tile, n-half). Stages sf[b, c0..c0+8, :] as f16
// into LDS (48 KB, stride-12-half rows -> ~4-way banks), then per query
// gathers 8 neighbors x 8 channels from LDS. No global feature gather, no
// transpose kernel, no cache dependence.
__global__ __launch_bounds__(256, 2) void accum_kernel(
    const float*    __restrict__ sf,   // [B,C,S]
    const unsigned* __restrict__ pk,   // [B,N,8] packed (f16 w | idx)
    float* __restrict__ out)           // [B,C,N]
{
    __shared__ unsigned short feat[SS * FSTR];   // 48 KB

    const int blk  = blockIdx.x;
    const int b    = blk >> 6;             // 64 blocks per batch
    const int ct   = (blk >> 1) & 31;      // channel tile 0..31
    const int half = blk & 1;              // n half
    const int t    = threadIdx.x;
    const int c0   = ct * 8;

    // ---- stage: thread <-> point s, 8 channels each, cvt f32->f16 ----
    const float* sfb = sf + ((long)b * CC + c0) * SS;
#pragma unroll
    for (int i = 0; i < SS / 256; ++i) {
        int s = i * 256 + t;
        float f[8];
#pragma unroll
        for (int c = 0; c < 8; ++c) f[c] = sfb[(long)c * SS + s];
        uint2 w0 = make_uint2(pack_h2(f[0], f[1]), pack_h2(f[2], f[3]));
        uint2 w1 = make_uint2(pack_h2(f[4], f[5]), pack_h2(f[6], f[7]));
        *(uint2*)&feat[s * FSTR]     = w0;     // ds_write_b64
        *(uint2*)&feat[s * FSTR + 4] = w1;
    }
    __syncthreads();

    const unsigned* pkb = pk + ((long)b * NN + half * 4096) * KNN;
    float* outb = out + ((long)b * CC + c0) * NN + half * 4096;

    for (int it = 0; it < 4096 / 256; ++it) {
        const int nrel = it * 256 + t;
        const uint4 pa = *(const uint4*)(pkb + (long)nrel * KNN);
        const uint4 pb = *(const uint4*)(pkb + (long)nrel * KNN + 4);
        const unsigned pks[8] = {pa.x, pa.y, pa.z, pa.w, pb.x, pb.y, pb.z, pb.w};

        float acc[8];
#pragma unroll
        for (int c = 0; c < 8; ++c) acc[c] = 0.f;

#pragma unroll
        for (int k = 0; k < KNN; ++k) {
            const unsigned p = pks[k];
            const int id = p & 0x7FF;
            const float w = __half2float(__ushort_as_half((unsigned short)(p >> 16)));
            const unsigned short* fp = &feat[id * FSTR];
            uint2 A = *(const uint2*)fp;         // ds_read_b64: ch 0-3
            uint2 B = *(const uint2*)(fp + 4);   // ds_read_b64: ch 4-7
            float2 f0 = unpack_h2(A.x), f1 = unpack_h2(A.y);
            float2 f2 = unpack_h2(B.x), f3 = unpack_h2(B.y);
            acc[0] = fmaf(w, f0.x, acc[0]);
            acc[1] = fmaf(w, f0.y, acc[1]);
            acc[2] = fmaf(w, f1.x, acc[2]);
            acc[3] = fmaf(w, f1.y, acc[3]);
            acc[4] = fmaf(w, f2.x, acc[4]);
            acc[5] = fmaf(w, f2.y, acc[5]);
            acc[6] = fmaf(w, f3.x, acc[6]);
            acc[7] = fmaf(w, f3.y, acc[7]);
        }

#pragma unroll
        for (int c = 0; c < 8; ++c)
            outb[(long)c * NN + nrel] = acc[c];   // coalesced per channel row
    }
}

extern "C" void kernel_launch(void* const* d_in, const int* in_sizes, int n_in,
                              void* d_out, int out_size, void* d_ws, size_t ws_size,
                              hipStream_t stream) {
    const float* xyz  = (const float*)d_in[0];   // [8,3,8192]
    const float* sxyz = (const float*)d_in[1];   // [8,3,2048]
    const float* sf   = (const float*)d_in[2];   // [8,256,2048]
    float* out = (float*)d_out;                  // [8,256,8192]

    unsigned* pkbuf = (unsigned*)d_ws;           // 2 MB packed (f16 w | idx)

    knn_kernel<<<dim3(BB * NN / QPB), dim3(256), 0, stream>>>(xyz, sxyz, pkbuf);
    accum_kernel<<<dim3(BB * 32 * 2), dim3(256), 0, stream>>>(sf, pkbuf, out);
}